// Round 2
// baseline (466.171 us; speedup 1.0000x reference)
//
#include <hip/hip_runtime.h>
#include <hip/hip_fp16.h>
#include <math.h>

#define NN 50000
#define NE 800000
#define GEPS 1e-15f
#define BN_EPS 1e-5f
#define NB 196  // (NN+255)/256

struct __align__(16) EdgeRec {
    int src;
    __half w[11];   // [0..4]=conv1, [5..9]=conv2, [10]=skip
    __half pad;
};

__device__ __forceinline__ float2 h2f(unsigned int u) {
    __half2 h = *reinterpret_cast<const __half2*>(&u);
    return __half22float2(h);
}

// inv[k*3+d] = -0.5/(eps + sigma^2): [0..14]=conv1, [15..29]=conv2, [30..32]=skip
__global__ void precompute_inv(const float* __restrict__ sig1, const float* __restrict__ sig2,
                               const float* __restrict__ sigs, float* __restrict__ inv) {
    int t = threadIdx.x;
    if (t < 15)      { float s = sig1[t];      inv[t] = -0.5f / (GEPS + s * s); }
    else if (t < 30) { float s = sig2[t - 15]; inv[t] = -0.5f / (GEPS + s * s); }
    else if (t < 33) { float s = sigs[t - 30]; inv[t] = -0.5f / (GEPS + s * s); }
}

__global__ void hist_kernel(const int* __restrict__ ei, int* __restrict__ deg) {
    int e = blockIdx.x * blockDim.x + threadIdx.x;
    if (e < NE) atomicAdd(&deg[ei[NE + e]], 1);
}

// ---- two-level scan ----
__global__ void block_reduce_kernel(const int* __restrict__ deg, int* __restrict__ bsum) {
    __shared__ int sh[256];
    int t = threadIdx.x;
    int i = blockIdx.x * 256 + t;
    sh[t] = (i < NN) ? deg[i] : 0;
    __syncthreads();
    for (int off = 128; off > 0; off >>= 1) {
        if (t < off) sh[t] += sh[t + off];
        __syncthreads();
    }
    if (t == 0) bsum[blockIdx.x] = sh[0];
}

__global__ void scan_partials_kernel(int* __restrict__ bsum) {
    __shared__ int sh[256];
    int t = threadIdx.x;
    int v = (t < NB) ? bsum[t] : 0;
    sh[t] = v;
    __syncthreads();
    for (int off = 1; off < 256; off <<= 1) {
        int u = (t >= off) ? sh[t - off] : 0;
        __syncthreads();
        sh[t] += u;
        __syncthreads();
    }
    if (t < NB) bsum[t] = sh[t] - v;  // exclusive
}

__global__ void block_scan_kernel(const int* __restrict__ deg, const int* __restrict__ bsum,
                                  int* __restrict__ rowstart, int* __restrict__ cursor) {
    __shared__ int sh[256];
    int t = threadIdx.x;
    int i = blockIdx.x * 256 + t;
    int v = (i < NN) ? deg[i] : 0;
    sh[t] = v;
    __syncthreads();
    for (int off = 1; off < 256; off <<= 1) {
        int u = (t >= off) ? sh[t - off] : 0;
        __syncthreads();
        sh[t] += u;
        __syncthreads();
    }
    int excl = sh[t] - v + bsum[blockIdx.x];
    if (i < NN) { rowstart[i] = excl; cursor[i] = excl; }
}

// scatter edges into CSR order as packed 32B records (src + 11 fp16 gaussian weights)
__global__ void reorder_kernel(const int* __restrict__ ei, const float* __restrict__ ea,
                               const float* __restrict__ mu1, const float* __restrict__ mu2,
                               const float* __restrict__ mus, const float* __restrict__ inv,
                               int* __restrict__ cursor, int4* __restrict__ recs) {
    int e = blockIdx.x * blockDim.x + threadIdx.x;
    if (e >= NE) return;
    int src = ei[e];
    int dst = ei[NE + e];
    float a0 = ea[e * 3 + 0], a1 = ea[e * 3 + 1], a2 = ea[e * 3 + 2];

    union { EdgeRec r; int4 q[2]; } u;
    u.r.src = src;
#pragma unroll
    for (int k = 0; k < 5; k++) {
        float d0 = a0 - mu1[k * 3 + 0], d1 = a1 - mu1[k * 3 + 1], d2 = a2 - mu1[k * 3 + 2];
        float ex = inv[k * 3] * d0 * d0 + inv[k * 3 + 1] * d1 * d1 + inv[k * 3 + 2] * d2 * d2;
        u.r.w[k] = __float2half(__expf(ex));
    }
#pragma unroll
    for (int k = 0; k < 5; k++) {
        float d0 = a0 - mu2[k * 3 + 0], d1 = a1 - mu2[k * 3 + 1], d2 = a2 - mu2[k * 3 + 2];
        float ex = inv[15 + k * 3] * d0 * d0 + inv[15 + k * 3 + 1] * d1 * d1 + inv[15 + k * 3 + 2] * d2 * d2;
        u.r.w[5 + k] = __float2half(__expf(ex));
    }
    {
        float d0 = a0 - mus[0], d1 = a1 - mus[1], d2 = a2 - mus[2];
        float ex = inv[30] * d0 * d0 + inv[31] * d1 * d1 + inv[32] * d2 * d2;
        u.r.w[10] = __float2half(__expf(ex));
    }
    u.r.pad = __float2half(0.f);

    int pos = atomicAdd(&cursor[dst], 1);
    recs[(size_t)pos * 2]     = u.q[0];
    recs[(size_t)pos * 2 + 1] = u.q[1];
}

// pass A projection: x -> PA[n][192] fp16 (0..159: g1-proj, 160..191: gs-proj),
//                    R1[n][32] fp32 (x@root1+b1), Rs[n][32] fp32 (x@roots+bs). block=256.
__global__ void projA_kernel(const float* __restrict__ x, const float* __restrict__ g1,
                             const float* __restrict__ gs, const float* __restrict__ root1,
                             const float* __restrict__ b1, const float* __restrict__ roots,
                             const float* __restrict__ bs, __half* __restrict__ PA,
                             float* __restrict__ R1, float* __restrict__ Rs) {
    const int t = threadIdx.x;
    float w[32];
    float b = 0.0f;
    if (t < 160) {
#pragma unroll
        for (int i = 0; i < 32; i++) w[i] = g1[i * 160 + t];
    } else if (t < 192) {
        int c = t - 160;
#pragma unroll
        for (int i = 0; i < 32; i++) w[i] = gs[i * 32 + c];
    } else if (t < 224) {
        int c = t - 192;
#pragma unroll
        for (int i = 0; i < 32; i++) w[i] = root1[i * 32 + c];
        b = b1[c];
    } else {
        int c = t - 224;
#pragma unroll
        for (int i = 0; i < 32; i++) w[i] = roots[i * 32 + c];
        b = bs[c];
    }
    __shared__ float xs[8 * 32];
    for (int n0 = blockIdx.x * 8; n0 < NN; n0 += gridDim.x * 8) {
        int rows = NN - n0; if (rows > 8) rows = 8;
        for (int j = t; j < rows * 32; j += 256) xs[j] = x[(size_t)n0 * 32 + j];
        __syncthreads();
        for (int r = 0; r < rows; r++) {
            float acc = b;
#pragma unroll
            for (int i = 0; i < 32; i++) acc += w[i] * xs[r * 32 + i];
            int n = n0 + r;
            if (t < 192) PA[(size_t)n * 192 + t] = __float2half(acc);
            else if (t < 224) R1[(size_t)n * 32 + (t - 192)] = acc;
            else Rs[(size_t)n * 32 + (t - 224)] = acc;
        }
        __syncthreads();
    }
}

// pass B projection fused with BN+ELU of pass-A conv output:
// h = elu(bn(c1)) computed on the fly; h -> PB[n][160] fp16, R2[n][32] fp32. block=192.
__global__ void projB_kernel(const float* __restrict__ c1, const float* __restrict__ stats,
                             const float* __restrict__ gam1, const float* __restrict__ bet1,
                             const float* __restrict__ g2, const float* __restrict__ root2,
                             const float* __restrict__ b2, __half* __restrict__ PB,
                             float* __restrict__ R2) {
    const int t = threadIdx.x;
    __shared__ float sc[32], sf[32];
    if (t < 32) {
        const float invN = 1.0f / (float)NN;
        float m = stats[t] * invN;
        float v = stats[32 + t] * invN - m * m;
        float s = gam1[t] * rsqrtf(v + BN_EPS);
        sc[t] = s;
        sf[t] = bet1[t] - m * s;
    }
    float w[32];
    float b = 0.0f;
    if (t < 160) {
#pragma unroll
        for (int i = 0; i < 32; i++) w[i] = g2[i * 160 + t];
    } else {
        int c = t - 160;
#pragma unroll
        for (int i = 0; i < 32; i++) w[i] = root2[i * 32 + c];
        b = b2[c];
    }
    __shared__ float xs[8 * 32];
    __syncthreads();   // sc/sf ready
    for (int n0 = blockIdx.x * 8; n0 < NN; n0 += gridDim.x * 8) {
        int rows = NN - n0; if (rows > 8) rows = 8;
        for (int j = t; j < rows * 32; j += 192) {
            int ch = j & 31;
            float hv = sc[ch] * c1[(size_t)n0 * 32 + j] + sf[ch];
            xs[j] = hv > 0.f ? hv : (__expf(hv) - 1.f);
        }
        __syncthreads();
        for (int r = 0; r < rows; r++) {
            float acc = b;
#pragma unroll
            for (int i = 0; i < 32; i++) acc += w[i] * xs[r * 32 + i];
            int n = n0 + r;
            if (t < 160) PB[(size_t)n * 160 + t] = __float2half(acc);
            else R2[(size_t)n * 32 + (t - 160)] = acc;
        }
        __syncthreads();
    }
}

// CSR node-gather aggregate v2. One wave per node; 8 groups of 8 lanes; group g handles
// edges i%8==g; each lane owns a channel QUAD (uint2 = 4 halves gather, float[4] accum).
// Record loaded as 2x int4 (one cache line). Cross-group reduce via shfl_xor(8/16/32).
// Fuses mean + root add + BN stats. SKIP adds the K=1 skip conv (pass A); !SKIP = pass B
// (weights w[5..9]).
template <bool SKIP>
__global__ __launch_bounds__(256, 8) void agg_kernel(
        const EdgeRec* __restrict__ recs, const int* __restrict__ rowstart,
        const int* __restrict__ deg, const __half* __restrict__ P, int strideHalf,
        const float* __restrict__ R, const float* __restrict__ Rs,
        float* __restrict__ c, float* __restrict__ cs, float* __restrict__ stats) {
    const int tid = blockIdx.x * blockDim.x + threadIdx.x;
    const int lane = threadIdx.x & 63;
    const int grp = lane >> 3;        // 0..7: edge subgroup
    const int ch4 = lane & 7;         // channel-quad index (channels 4*ch4 .. 4*ch4+3)
    const int wavesTotal = (gridDim.x * blockDim.x) >> 6;
    const int wid = tid >> 6;

    float s1[4] = {0.f, 0.f, 0.f, 0.f}, q1[4] = {0.f, 0.f, 0.f, 0.f};
    float ss[4] = {0.f, 0.f, 0.f, 0.f}, qs[4] = {0.f, 0.f, 0.f, 0.f};

    for (int n = wid; n < NN; n += wavesTotal) {
        const int start = rowstart[n];
        const int d = deg[n];
        float m[4] = {0.f, 0.f, 0.f, 0.f};
        float mk[4] = {0.f, 0.f, 0.f, 0.f};
        for (int i = grp; i < d; i += 8) {
            const int4* rp = (const int4*)(recs + (size_t)(start + i));
            int4 r0 = rp[0];
            int4 r1 = rp[1];
            const uint2* prow = (const uint2*)(P + (size_t)r0.x * strideHalf) + ch4;
            uint2 g0 = prow[0];
            uint2 g1 = prow[8];
            uint2 g2 = prow[16];
            uint2 g3 = prow[24];
            uint2 g4 = prow[32];
            uint2 gS;
            if (SKIP) gS = prow[40];
            float w0, w1, w2, w3, w4, wS;
            if (SKIP) {           // conv1 weights w[0..4] + skip w[10]
                float2 ab = h2f((unsigned)r0.y);
                float2 cd = h2f((unsigned)r0.z);
                float2 ef = h2f((unsigned)r0.w);
                w0 = ab.x; w1 = ab.y; w2 = cd.x; w3 = cd.y; w4 = ef.x;
                wS = h2f((unsigned)r1.z).x;
            } else {              // conv2 weights w[5..9]
                w0 = h2f((unsigned)r0.w).y;
                float2 ab = h2f((unsigned)r1.x);
                float2 cd = h2f((unsigned)r1.y);
                w1 = ab.x; w2 = ab.y; w3 = cd.x; w4 = cd.y;
            }
            {
                float2 lo = h2f(g0.x), hi = h2f(g0.y);
                m[0] += w0 * lo.x; m[1] += w0 * lo.y; m[2] += w0 * hi.x; m[3] += w0 * hi.y;
            }
            {
                float2 lo = h2f(g1.x), hi = h2f(g1.y);
                m[0] += w1 * lo.x; m[1] += w1 * lo.y; m[2] += w1 * hi.x; m[3] += w1 * hi.y;
            }
            {
                float2 lo = h2f(g2.x), hi = h2f(g2.y);
                m[0] += w2 * lo.x; m[1] += w2 * lo.y; m[2] += w2 * hi.x; m[3] += w2 * hi.y;
            }
            {
                float2 lo = h2f(g3.x), hi = h2f(g3.y);
                m[0] += w3 * lo.x; m[1] += w3 * lo.y; m[2] += w3 * hi.x; m[3] += w3 * hi.y;
            }
            {
                float2 lo = h2f(g4.x), hi = h2f(g4.y);
                m[0] += w4 * lo.x; m[1] += w4 * lo.y; m[2] += w4 * hi.x; m[3] += w4 * hi.y;
            }
            if (SKIP) {
                float2 lo = h2f(gS.x), hi = h2f(gS.y);
                mk[0] += wS * lo.x; mk[1] += wS * lo.y; mk[2] += wS * hi.x; mk[3] += wS * hi.y;
            }
        }
#pragma unroll
        for (int j = 0; j < 4; j++) {
            m[j] += __shfl_xor(m[j], 8, 64);
            m[j] += __shfl_xor(m[j], 16, 64);
            m[j] += __shfl_xor(m[j], 32, 64);
        }
        if (SKIP) {
#pragma unroll
            for (int j = 0; j < 4; j++) {
                mk[j] += __shfl_xor(mk[j], 8, 64);
                mk[j] += __shfl_xor(mk[j], 16, 64);
                mk[j] += __shfl_xor(mk[j], 32, 64);
            }
        }
        const float invd = 1.0f / fmaxf((float)d, 1.0f);
        if (grp == 0) {
            float4 rv = ((const float4*)(R + (size_t)n * 32))[ch4];
            float v0 = m[0] * invd + rv.x;
            float v1 = m[1] * invd + rv.y;
            float v2 = m[2] * invd + rv.z;
            float v3 = m[3] * invd + rv.w;
            ((float4*)(c + (size_t)n * 32))[ch4] = make_float4(v0, v1, v2, v3);
            s1[0] += v0; s1[1] += v1; s1[2] += v2; s1[3] += v3;
            q1[0] += v0 * v0; q1[1] += v1 * v1; q1[2] += v2 * v2; q1[3] += v3 * v3;
            if (SKIP) {
                float4 rs = ((const float4*)(Rs + (size_t)n * 32))[ch4];
                float u0 = mk[0] * invd + rs.x;
                float u1 = mk[1] * invd + rs.y;
                float u2 = mk[2] * invd + rs.z;
                float u3 = mk[3] * invd + rs.w;
                ((float4*)(cs + (size_t)n * 32))[ch4] = make_float4(u0, u1, u2, u3);
                ss[0] += u0; ss[1] += u1; ss[2] += u2; ss[3] += u3;
                qs[0] += u0 * u0; qs[1] += u1 * u1; qs[2] += u2 * u2; qs[3] += u3 * u3;
            }
        }
    }
    __shared__ float sh[128];
    const int t = threadIdx.x;
    if (t < 128) sh[t] = 0.f;
    __syncthreads();
    if (grp == 0) {
#pragma unroll
        for (int j = 0; j < 4; j++) {
            int ch = ch4 * 4 + j;
            atomicAdd(&sh[ch], s1[j]);
            atomicAdd(&sh[32 + ch], q1[j]);
            if (SKIP) {
                atomicAdd(&sh[64 + ch], ss[j]);
                atomicAdd(&sh[96 + ch], qs[j]);
            }
        }
    }
    __syncthreads();
    if (SKIP) { if (t < 128) atomicAdd(&stats[t], sh[t]); }
    else      { if (t < 64)  atomicAdd(&stats[t], sh[t]); }
}

// out = elu( bn2(c2) + bn_s(cs) ). stats: [0..63]=pass A conv, [64..127]=pass A skip,
// [128..191]=pass B conv.
__global__ void apply2_kernel(const float* __restrict__ c2, const float* __restrict__ cs,
                              const float* __restrict__ stats, const float* __restrict__ gam2,
                              const float* __restrict__ bet2, const float* __restrict__ gams,
                              const float* __restrict__ bets, float* __restrict__ out) {
    int idx = blockIdx.x * blockDim.x + threadIdx.x;
    if (idx >= NN * 32) return;
    int ch = idx & 31;
    const float invN = 1.0f / (float)NN;
    float m2 = stats[128 + ch] * invN;
    float v2 = stats[160 + ch] * invN - m2 * m2;
    float ms = stats[64 + ch] * invN;
    float vs = stats[96 + ch] * invN - ms * ms;
    float bn2 = gam2[ch] * (c2[idx] - m2) * rsqrtf(v2 + BN_EPS) + bet2[ch];
    float bns = gams[ch] * (cs[idx] - ms) * rsqrtf(vs + BN_EPS) + bets[ch];
    float o = bn2 + bns;
    out[idx] = o > 0.f ? o : (__expf(o) - 1.f);
}

extern "C" void kernel_launch(void* const* d_in, const int* in_sizes, int n_in,
                              void* d_out, int out_size, void* d_ws, size_t ws_size,
                              hipStream_t stream) {
    const float* x     = (const float*)d_in[0];
    const float* ea    = (const float*)d_in[1];
    const float* g1    = (const float*)d_in[2];
    const float* mu1   = (const float*)d_in[3];
    const float* sig1  = (const float*)d_in[4];
    const float* root1 = (const float*)d_in[5];
    const float* b1    = (const float*)d_in[6];
    const float* gam1  = (const float*)d_in[7];
    const float* bet1  = (const float*)d_in[8];
    const float* g2    = (const float*)d_in[9];
    const float* mu2   = (const float*)d_in[10];
    const float* sig2  = (const float*)d_in[11];
    const float* root2 = (const float*)d_in[12];
    const float* b2    = (const float*)d_in[13];
    const float* gam2  = (const float*)d_in[14];
    const float* bet2  = (const float*)d_in[15];
    const float* gs    = (const float*)d_in[16];
    const float* mus   = (const float*)d_in[17];
    const float* sigs  = (const float*)d_in[18];
    const float* roots = (const float*)d_in[19];
    const float* bs    = (const float*)d_in[20];
    const float* gams  = (const float*)d_in[21];
    const float* bets  = (const float*)d_in[22];
    const int*   ei    = (const int*)d_in[23];
    float* out = (float*)d_out;

    // ---- workspace layout ----
    char* w = (char*)d_ws;
    __half* PA   = (__half*)w;      w += (size_t)NN * 192 * 2;  // 19.2 MB (reused as PB)
    float*  R1   = (float*)w;       w += (size_t)NN * 32 * 4;   // (reused as R2)
    float*  Rs   = (float*)w;       w += (size_t)NN * 32 * 4;
    float*  c1   = (float*)w;       w += (size_t)NN * 32 * 4;   // (reused as c2)
    float*  cs   = (float*)w;       w += (size_t)NN * 32 * 4;
    EdgeRec* recs = (EdgeRec*)w;    w += (size_t)NE * 32;       // 25.6 MB
    int*    deg  = (int*)w;         w += (size_t)NN * 4;
    int*    rowstart = (int*)w;     w += (size_t)NN * 4;
    int*    cursor   = (int*)w;     w += (size_t)NN * 4;
    int*    bsum = (int*)w;         w += 256 * 4;
    float*  stats = (float*)w;      w += 256 * 4;               // [0..127]=pass A, [128..191]=pass B
    float*  inv   = (float*)w;      w += 64 * 4;

    const int edgeBlocks  = (NE + 255) / 256;
    const int applyBlocks = (NN * 32 + 255) / 256;

    hipMemsetAsync(deg, 0, NN * sizeof(int), stream);
    hipMemsetAsync(stats, 0, 256 * sizeof(float), stream);
    precompute_inv<<<1, 64, 0, stream>>>(sig1, sig2, sigs, inv);

    // ---- CSR build (once, shared by all 3 convs) ----
    hist_kernel<<<edgeBlocks, 256, 0, stream>>>(ei, deg);
    block_reduce_kernel<<<NB, 256, 0, stream>>>(deg, bsum);
    scan_partials_kernel<<<1, 256, 0, stream>>>(bsum);
    block_scan_kernel<<<NB, 256, 0, stream>>>(deg, bsum, rowstart, cursor);
    reorder_kernel<<<edgeBlocks, 256, 0, stream>>>(ei, ea, mu1, mu2, mus, inv, cursor,
                                                   (int4*)recs);

    // ---- pass A: conv1 + skip fused ----
    projA_kernel<<<512, 256, 0, stream>>>(x, g1, gs, root1, b1, roots, bs, PA, R1, Rs);
    agg_kernel<true><<<2048, 256, 0, stream>>>(recs, rowstart, deg, (const __half*)PA, 192,
                                               R1, Rs, c1, cs, stats);

    // ---- pass B: projB fuses elu(bn(c1)); conv2; then out = elu(bn(c2) + bn(cs)) ----
    projB_kernel<<<512, 192, 0, stream>>>(c1, stats, gam1, bet1, g2, root2, b2, PA, R1);
    agg_kernel<false><<<2048, 256, 0, stream>>>(recs, rowstart, deg, (const __half*)PA, 160,
                                                R1, nullptr, c1, nullptr, stats + 128);
    apply2_kernel<<<applyBlocks, 256, 0, stream>>>(c1, cs, stats, gam2, bet2, gams, bets, out);
}

// Round 3
// 446.178 us; speedup vs baseline: 1.0448x; 1.0448x over previous
//
#include <hip/hip_runtime.h>
#include <hip/hip_fp16.h>
#include <math.h>

#define NN 50000
#define NE 800000
#define GEPS 1e-15f
#define BN_EPS 1e-5f
#define NB 196  // (NN+255)/256

struct __align__(16) EdgeRec {
    int src;
    __half w[11];   // [0..4]=conv1, [5..9]=conv2, [10]=skip
    __half pad;
};

__device__ __forceinline__ float2 h2f(unsigned int u) {
    __half2 h = *reinterpret_cast<const __half2*>(&u);
    return __half22float2(h);
}

// inv[k*3+d] = -0.5/(eps + sigma^2): [0..14]=conv1, [15..29]=conv2, [30..32]=skip
__global__ void precompute_inv(const float* __restrict__ sig1, const float* __restrict__ sig2,
                               const float* __restrict__ sigs, float* __restrict__ inv) {
    int t = threadIdx.x;
    if (t < 15)      { float s = sig1[t];      inv[t] = -0.5f / (GEPS + s * s); }
    else if (t < 30) { float s = sig2[t - 15]; inv[t] = -0.5f / (GEPS + s * s); }
    else if (t < 33) { float s = sigs[t - 30]; inv[t] = -0.5f / (GEPS + s * s); }
}

__global__ void hist_kernel(const int* __restrict__ ei, int* __restrict__ deg) {
    int e = blockIdx.x * blockDim.x + threadIdx.x;
    if (e < NE) atomicAdd(&deg[ei[NE + e]], 1);
}

// ---- two-level scan ----
__global__ void block_reduce_kernel(const int* __restrict__ deg, int* __restrict__ bsum) {
    __shared__ int sh[256];
    int t = threadIdx.x;
    int i = blockIdx.x * 256 + t;
    sh[t] = (i < NN) ? deg[i] : 0;
    __syncthreads();
    for (int off = 128; off > 0; off >>= 1) {
        if (t < off) sh[t] += sh[t + off];
        __syncthreads();
    }
    if (t == 0) bsum[blockIdx.x] = sh[0];
}

__global__ void scan_partials_kernel(int* __restrict__ bsum) {
    __shared__ int sh[256];
    int t = threadIdx.x;
    int v = (t < NB) ? bsum[t] : 0;
    sh[t] = v;
    __syncthreads();
    for (int off = 1; off < 256; off <<= 1) {
        int u = (t >= off) ? sh[t - off] : 0;
        __syncthreads();
        sh[t] += u;
        __syncthreads();
    }
    if (t < NB) bsum[t] = sh[t] - v;  // exclusive
}

__global__ void block_scan_kernel(const int* __restrict__ deg, const int* __restrict__ bsum,
                                  int* __restrict__ rowstart, int* __restrict__ cursor) {
    __shared__ int sh[256];
    int t = threadIdx.x;
    int i = blockIdx.x * 256 + t;
    int v = (i < NN) ? deg[i] : 0;
    sh[t] = v;
    __syncthreads();
    for (int off = 1; off < 256; off <<= 1) {
        int u = (t >= off) ? sh[t - off] : 0;
        __syncthreads();
        sh[t] += u;
        __syncthreads();
    }
    int excl = sh[t] - v + bsum[blockIdx.x];
    if (i < NN) { rowstart[i] = excl; cursor[i] = excl; }
}

// scatter edges into CSR order as packed 32B records (src + 11 fp16 gaussian weights)
__global__ void reorder_kernel(const int* __restrict__ ei, const float* __restrict__ ea,
                               const float* __restrict__ mu1, const float* __restrict__ mu2,
                               const float* __restrict__ mus, const float* __restrict__ inv,
                               int* __restrict__ cursor, int4* __restrict__ recs) {
    int e = blockIdx.x * blockDim.x + threadIdx.x;
    if (e >= NE) return;
    int src = ei[e];
    int dst = ei[NE + e];
    float a0 = ea[e * 3 + 0], a1 = ea[e * 3 + 1], a2 = ea[e * 3 + 2];

    union { EdgeRec r; int4 q[2]; } u;
    u.r.src = src;
#pragma unroll
    for (int k = 0; k < 5; k++) {
        float d0 = a0 - mu1[k * 3 + 0], d1 = a1 - mu1[k * 3 + 1], d2 = a2 - mu1[k * 3 + 2];
        float ex = inv[k * 3] * d0 * d0 + inv[k * 3 + 1] * d1 * d1 + inv[k * 3 + 2] * d2 * d2;
        u.r.w[k] = __float2half(__expf(ex));
    }
#pragma unroll
    for (int k = 0; k < 5; k++) {
        float d0 = a0 - mu2[k * 3 + 0], d1 = a1 - mu2[k * 3 + 1], d2 = a2 - mu2[k * 3 + 2];
        float ex = inv[15 + k * 3] * d0 * d0 + inv[15 + k * 3 + 1] * d1 * d1 + inv[15 + k * 3 + 2] * d2 * d2;
        u.r.w[5 + k] = __float2half(__expf(ex));
    }
    {
        float d0 = a0 - mus[0], d1 = a1 - mus[1], d2 = a2 - mus[2];
        float ex = inv[30] * d0 * d0 + inv[31] * d1 * d1 + inv[32] * d2 * d2;
        u.r.w[10] = __float2half(__expf(ex));
    }
    u.r.pad = __float2half(0.f);

    int pos = atomicAdd(&cursor[dst], 1);
    recs[(size_t)pos * 2]     = u.q[0];
    recs[(size_t)pos * 2 + 1] = u.q[1];
}

// pass A projection: x -> PA[n][192] fp16 (0..159: g1-proj, 160..191: gs-proj),
//                    R1[n][32] fp32 (x@root1+b1), Rs[n][32] fp32 (x@roots+bs). block=256.
__global__ void projA_kernel(const float* __restrict__ x, const float* __restrict__ g1,
                             const float* __restrict__ gs, const float* __restrict__ root1,
                             const float* __restrict__ b1, const float* __restrict__ roots,
                             const float* __restrict__ bs, __half* __restrict__ PA,
                             float* __restrict__ R1, float* __restrict__ Rs) {
    const int t = threadIdx.x;
    float w[32];
    float b = 0.0f;
    if (t < 160) {
#pragma unroll
        for (int i = 0; i < 32; i++) w[i] = g1[i * 160 + t];
    } else if (t < 192) {
        int c = t - 160;
#pragma unroll
        for (int i = 0; i < 32; i++) w[i] = gs[i * 32 + c];
    } else if (t < 224) {
        int c = t - 192;
#pragma unroll
        for (int i = 0; i < 32; i++) w[i] = root1[i * 32 + c];
        b = b1[c];
    } else {
        int c = t - 224;
#pragma unroll
        for (int i = 0; i < 32; i++) w[i] = roots[i * 32 + c];
        b = bs[c];
    }
    __shared__ float xs[8 * 32];
    for (int n0 = blockIdx.x * 8; n0 < NN; n0 += gridDim.x * 8) {
        int rows = NN - n0; if (rows > 8) rows = 8;
        for (int j = t; j < rows * 32; j += 256) xs[j] = x[(size_t)n0 * 32 + j];
        __syncthreads();
        for (int r = 0; r < rows; r++) {
            float acc = b;
#pragma unroll
            for (int i = 0; i < 32; i++) acc += w[i] * xs[r * 32 + i];
            int n = n0 + r;
            if (t < 192) PA[(size_t)n * 192 + t] = __float2half(acc);
            else if (t < 224) R1[(size_t)n * 32 + (t - 192)] = acc;
            else Rs[(size_t)n * 32 + (t - 224)] = acc;
        }
        __syncthreads();
    }
}

// pass B projection fused with BN+ELU of pass-A conv output:
// h = elu(bn(c1)) computed on the fly; h -> PB[n][160] fp16, R2[n][32] fp32. block=192.
__global__ void projB_kernel(const float* __restrict__ c1, const float* __restrict__ stats,
                             const float* __restrict__ gam1, const float* __restrict__ bet1,
                             const float* __restrict__ g2, const float* __restrict__ root2,
                             const float* __restrict__ b2, __half* __restrict__ PB,
                             float* __restrict__ R2) {
    const int t = threadIdx.x;
    __shared__ float sc[32], sf[32];
    if (t < 32) {
        const float invN = 1.0f / (float)NN;
        float m = stats[t] * invN;
        float v = stats[32 + t] * invN - m * m;
        float s = gam1[t] * rsqrtf(v + BN_EPS);
        sc[t] = s;
        sf[t] = bet1[t] - m * s;
    }
    float w[32];
    float b = 0.0f;
    if (t < 160) {
#pragma unroll
        for (int i = 0; i < 32; i++) w[i] = g2[i * 160 + t];
    } else {
        int c = t - 160;
#pragma unroll
        for (int i = 0; i < 32; i++) w[i] = root2[i * 32 + c];
        b = b2[c];
    }
    __shared__ float xs[8 * 32];
    __syncthreads();   // sc/sf ready
    for (int n0 = blockIdx.x * 8; n0 < NN; n0 += gridDim.x * 8) {
        int rows = NN - n0; if (rows > 8) rows = 8;
        for (int j = t; j < rows * 32; j += 192) {
            int ch = j & 31;
            float hv = sc[ch] * c1[(size_t)n0 * 32 + j] + sf[ch];
            xs[j] = hv > 0.f ? hv : (__expf(hv) - 1.f);
        }
        __syncthreads();
        for (int r = 0; r < rows; r++) {
            float acc = b;
#pragma unroll
            for (int i = 0; i < 32; i++) acc += w[i] * xs[r * 32 + i];
            int n = n0 + r;
            if (t < 160) PB[(size_t)n * 160 + t] = __float2half(acc);
            else R2[(size_t)n * 32 + (t - 160)] = acc;
        }
        __syncthreads();
    }
}

// CSR node-gather aggregate v3. One wave per node; 8 groups of 8 lanes; group g handles
// edges i%8==g; each lane owns a channel QUAD (uint2 = 4 halves gather, float[4] accum).
// Record loaded as 2x int4 (one cache line). Cross-group reduce via shfl_xor(8/16/32).
// Fuses mean + root add + BN stats. SKIP adds the K=1 skip conv (pass A); !SKIP = pass B
// (weights w[5..9]).
// launch_bounds (256,4): cap 128 VGPRs — (256,8) in v2 capped at 64 and spilled
// (WRITE_SIZE 13MB->140MB of scratch traffic, +35% dur). ~55 live regs fit under 128.
template <bool SKIP>
__global__ __launch_bounds__(256, 4) void agg_kernel(
        const EdgeRec* __restrict__ recs, const int* __restrict__ rowstart,
        const int* __restrict__ deg, const __half* __restrict__ P, int strideHalf,
        const float* __restrict__ R, const float* __restrict__ Rs,
        float* __restrict__ c, float* __restrict__ cs, float* __restrict__ stats) {
    const int tid = blockIdx.x * blockDim.x + threadIdx.x;
    const int lane = threadIdx.x & 63;
    const int grp = lane >> 3;        // 0..7: edge subgroup
    const int ch4 = lane & 7;         // channel-quad index (channels 4*ch4 .. 4*ch4+3)
    const int wavesTotal = (gridDim.x * blockDim.x) >> 6;
    const int wid = tid >> 6;

    float s1[4] = {0.f, 0.f, 0.f, 0.f}, q1[4] = {0.f, 0.f, 0.f, 0.f};
    float ss[4] = {0.f, 0.f, 0.f, 0.f}, qs[4] = {0.f, 0.f, 0.f, 0.f};

    for (int n = wid; n < NN; n += wavesTotal) {
        const int start = rowstart[n];
        const int d = deg[n];
        float m[4] = {0.f, 0.f, 0.f, 0.f};
        float mk[4] = {0.f, 0.f, 0.f, 0.f};
        for (int i = grp; i < d; i += 8) {
            const int4* rp = (const int4*)(recs + (size_t)(start + i));
            int4 r0 = rp[0];
            int4 r1 = rp[1];
            const uint2* prow = (const uint2*)(P + (size_t)r0.x * strideHalf) + ch4;
            uint2 g0 = prow[0];
            uint2 g1 = prow[8];
            uint2 g2 = prow[16];
            uint2 g3 = prow[24];
            uint2 g4 = prow[32];
            uint2 gS;
            if (SKIP) gS = prow[40];
            float w0, w1, w2, w3, w4, wS;
            if (SKIP) {           // conv1 weights w[0..4] + skip w[10]
                float2 ab = h2f((unsigned)r0.y);
                float2 cd = h2f((unsigned)r0.z);
                float2 ef = h2f((unsigned)r0.w);
                w0 = ab.x; w1 = ab.y; w2 = cd.x; w3 = cd.y; w4 = ef.x;
                wS = h2f((unsigned)r1.z).x;
            } else {              // conv2 weights w[5..9]
                w0 = h2f((unsigned)r0.w).y;
                float2 ab = h2f((unsigned)r1.x);
                float2 cd = h2f((unsigned)r1.y);
                w1 = ab.x; w2 = ab.y; w3 = cd.x; w4 = cd.y;
            }
            {
                float2 lo = h2f(g0.x), hi = h2f(g0.y);
                m[0] += w0 * lo.x; m[1] += w0 * lo.y; m[2] += w0 * hi.x; m[3] += w0 * hi.y;
            }
            {
                float2 lo = h2f(g1.x), hi = h2f(g1.y);
                m[0] += w1 * lo.x; m[1] += w1 * lo.y; m[2] += w1 * hi.x; m[3] += w1 * hi.y;
            }
            {
                float2 lo = h2f(g2.x), hi = h2f(g2.y);
                m[0] += w2 * lo.x; m[1] += w2 * lo.y; m[2] += w2 * hi.x; m[3] += w2 * hi.y;
            }
            {
                float2 lo = h2f(g3.x), hi = h2f(g3.y);
                m[0] += w3 * lo.x; m[1] += w3 * lo.y; m[2] += w3 * hi.x; m[3] += w3 * hi.y;
            }
            {
                float2 lo = h2f(g4.x), hi = h2f(g4.y);
                m[0] += w4 * lo.x; m[1] += w4 * lo.y; m[2] += w4 * hi.x; m[3] += w4 * hi.y;
            }
            if (SKIP) {
                float2 lo = h2f(gS.x), hi = h2f(gS.y);
                mk[0] += wS * lo.x; mk[1] += wS * lo.y; mk[2] += wS * hi.x; mk[3] += wS * hi.y;
            }
        }
#pragma unroll
        for (int j = 0; j < 4; j++) {
            m[j] += __shfl_xor(m[j], 8, 64);
            m[j] += __shfl_xor(m[j], 16, 64);
            m[j] += __shfl_xor(m[j], 32, 64);
        }
        if (SKIP) {
#pragma unroll
            for (int j = 0; j < 4; j++) {
                mk[j] += __shfl_xor(mk[j], 8, 64);
                mk[j] += __shfl_xor(mk[j], 16, 64);
                mk[j] += __shfl_xor(mk[j], 32, 64);
            }
        }
        const float invd = 1.0f / fmaxf((float)d, 1.0f);
        if (grp == 0) {
            float4 rv = ((const float4*)(R + (size_t)n * 32))[ch4];
            float v0 = m[0] * invd + rv.x;
            float v1 = m[1] * invd + rv.y;
            float v2 = m[2] * invd + rv.z;
            float v3 = m[3] * invd + rv.w;
            ((float4*)(c + (size_t)n * 32))[ch4] = make_float4(v0, v1, v2, v3);
            s1[0] += v0; s1[1] += v1; s1[2] += v2; s1[3] += v3;
            q1[0] += v0 * v0; q1[1] += v1 * v1; q1[2] += v2 * v2; q1[3] += v3 * v3;
            if (SKIP) {
                float4 rs = ((const float4*)(Rs + (size_t)n * 32))[ch4];
                float u0 = mk[0] * invd + rs.x;
                float u1 = mk[1] * invd + rs.y;
                float u2 = mk[2] * invd + rs.z;
                float u3 = mk[3] * invd + rs.w;
                ((float4*)(cs + (size_t)n * 32))[ch4] = make_float4(u0, u1, u2, u3);
                ss[0] += u0; ss[1] += u1; ss[2] += u2; ss[3] += u3;
                qs[0] += u0 * u0; qs[1] += u1 * u1; qs[2] += u2 * u2; qs[3] += u3 * u3;
            }
        }
    }
    __shared__ float sh[128];
    const int t = threadIdx.x;
    if (t < 128) sh[t] = 0.f;
    __syncthreads();
    if (grp == 0) {
#pragma unroll
        for (int j = 0; j < 4; j++) {
            int ch = ch4 * 4 + j;
            atomicAdd(&sh[ch], s1[j]);
            atomicAdd(&sh[32 + ch], q1[j]);
            if (SKIP) {
                atomicAdd(&sh[64 + ch], ss[j]);
                atomicAdd(&sh[96 + ch], qs[j]);
            }
        }
    }
    __syncthreads();
    if (SKIP) { if (t < 128) atomicAdd(&stats[t], sh[t]); }
    else      { if (t < 64)  atomicAdd(&stats[t], sh[t]); }
}

// out = elu( bn2(c2) + bn_s(cs) ). stats: [0..63]=pass A conv, [64..127]=pass A skip,
// [128..191]=pass B conv.
__global__ void apply2_kernel(const float* __restrict__ c2, const float* __restrict__ cs,
                              const float* __restrict__ stats, const float* __restrict__ gam2,
                              const float* __restrict__ bet2, const float* __restrict__ gams,
                              const float* __restrict__ bets, float* __restrict__ out) {
    int idx = blockIdx.x * blockDim.x + threadIdx.x;
    if (idx >= NN * 32) return;
    int ch = idx & 31;
    const float invN = 1.0f / (float)NN;
    float m2 = stats[128 + ch] * invN;
    float v2 = stats[160 + ch] * invN - m2 * m2;
    float ms = stats[64 + ch] * invN;
    float vs = stats[96 + ch] * invN - ms * ms;
    float bn2 = gam2[ch] * (c2[idx] - m2) * rsqrtf(v2 + BN_EPS) + bet2[ch];
    float bns = gams[ch] * (cs[idx] - ms) * rsqrtf(vs + BN_EPS) + bets[ch];
    float o = bn2 + bns;
    out[idx] = o > 0.f ? o : (__expf(o) - 1.f);
}

extern "C" void kernel_launch(void* const* d_in, const int* in_sizes, int n_in,
                              void* d_out, int out_size, void* d_ws, size_t ws_size,
                              hipStream_t stream) {
    const float* x     = (const float*)d_in[0];
    const float* ea    = (const float*)d_in[1];
    const float* g1    = (const float*)d_in[2];
    const float* mu1   = (const float*)d_in[3];
    const float* sig1  = (const float*)d_in[4];
    const float* root1 = (const float*)d_in[5];
    const float* b1    = (const float*)d_in[6];
    const float* gam1  = (const float*)d_in[7];
    const float* bet1  = (const float*)d_in[8];
    const float* g2    = (const float*)d_in[9];
    const float* mu2   = (const float*)d_in[10];
    const float* sig2  = (const float*)d_in[11];
    const float* root2 = (const float*)d_in[12];
    const float* b2    = (const float*)d_in[13];
    const float* gam2  = (const float*)d_in[14];
    const float* bet2  = (const float*)d_in[15];
    const float* gs    = (const float*)d_in[16];
    const float* mus   = (const float*)d_in[17];
    const float* sigs  = (const float*)d_in[18];
    const float* roots = (const float*)d_in[19];
    const float* bs    = (const float*)d_in[20];
    const float* gams  = (const float*)d_in[21];
    const float* bets  = (const float*)d_in[22];
    const int*   ei    = (const int*)d_in[23];
    float* out = (float*)d_out;

    // ---- workspace layout ----
    char* w = (char*)d_ws;
    __half* PA   = (__half*)w;      w += (size_t)NN * 192 * 2;  // 19.2 MB (reused as PB)
    float*  R1   = (float*)w;       w += (size_t)NN * 32 * 4;   // (reused as R2)
    float*  Rs   = (float*)w;       w += (size_t)NN * 32 * 4;
    float*  c1   = (float*)w;       w += (size_t)NN * 32 * 4;   // (reused as c2)
    float*  cs   = (float*)w;       w += (size_t)NN * 32 * 4;
    EdgeRec* recs = (EdgeRec*)w;    w += (size_t)NE * 32;       // 25.6 MB
    int*    deg  = (int*)w;         w += (size_t)NN * 4;
    int*    rowstart = (int*)w;     w += (size_t)NN * 4;
    int*    cursor   = (int*)w;     w += (size_t)NN * 4;
    int*    bsum = (int*)w;         w += 256 * 4;
    float*  stats = (float*)w;      w += 256 * 4;               // [0..127]=pass A, [128..191]=pass B
    float*  inv   = (float*)w;      w += 64 * 4;

    const int edgeBlocks  = (NE + 255) / 256;
    const int applyBlocks = (NN * 32 + 255) / 256;

    hipMemsetAsync(deg, 0, NN * sizeof(int), stream);
    hipMemsetAsync(stats, 0, 256 * sizeof(float), stream);
    precompute_inv<<<1, 64, 0, stream>>>(sig1, sig2, sigs, inv);

    // ---- CSR build (once, shared by all 3 convs) ----
    hist_kernel<<<edgeBlocks, 256, 0, stream>>>(ei, deg);
    block_reduce_kernel<<<NB, 256, 0, stream>>>(deg, bsum);
    scan_partials_kernel<<<1, 256, 0, stream>>>(bsum);
    block_scan_kernel<<<NB, 256, 0, stream>>>(deg, bsum, rowstart, cursor);
    reorder_kernel<<<edgeBlocks, 256, 0, stream>>>(ei, ea, mu1, mu2, mus, inv, cursor,
                                                   (int4*)recs);

    // ---- pass A: conv1 + skip fused ----
    projA_kernel<<<512, 256, 0, stream>>>(x, g1, gs, root1, b1, roots, bs, PA, R1, Rs);
    agg_kernel<true><<<2048, 256, 0, stream>>>(recs, rowstart, deg, (const __half*)PA, 192,
                                               R1, Rs, c1, cs, stats);

    // ---- pass B: projB fuses elu(bn(c1)); conv2; then out = elu(bn(c2) + bn(cs)) ----
    projB_kernel<<<512, 192, 0, stream>>>(c1, stats, gam1, bet1, g2, root2, b2, PA, R1);
    agg_kernel<false><<<2048, 256, 0, stream>>>(recs, rowstart, deg, (const __half*)PA, 160,
                                                R1, nullptr, c1, nullptr, stats + 128);
    apply2_kernel<<<applyBlocks, 256, 0, stream>>>(c1, cs, stats, gam2, bet2, gams, bets, out);
}